// Round 3
// baseline (436.334 us; speedup 1.0000x reference)
//
#include <hip/hip_runtime.h>
#include <math.h>

// Problem constants (fixed by setup_inputs)
#define BB 512
#define CC 480              // C1*C2 = 16*30 channels per batch
#define HW 225              // 15*15 pixels per channel
#define CHW (CC * HW)       // 108000 floats per batch
#define NF4 (CHW / 4)       // 27000 float4 per batch
#define NGRP (CC / 4)       // 120 groups of 4 channels (900 floats = 225 f4)
#define NGRP_TOTAL (BB * NGRP)  // 61440 groups over the whole tensor

// Kernel A (reduce): 1920 blocks x 256 thr = 7680 waves, exactly 8 groups/wave.
#define RED_BLOCKS 1920
#define RED_THREADS 256
#define RED_WAVES (RED_BLOCKS * (RED_THREADS / 64))

// Kernel B (gate+scale): 8 chunks per batch, 60 whole channels per chunk.
#define CHUNKS 8
#define CHUNK_F4 (NF4 / CHUNKS)   // 3375 float4 per chunk
#define CHUNK_CH (CC / CHUNKS)    // 60 channels per chunk (13500/225)
#define SC_THREADS 256
#define SC_FULL_ITERS (CHUNK_F4 / SC_THREADS)        // 13
#define SC_TAIL (CHUNK_F4 - SC_FULL_ITERS * SC_THREADS)  // 47

using f4 = __attribute__((ext_vector_type(4))) float;

__device__ __forceinline__ float sigmoidf(float v) {
    return 1.0f / (1.0f + __expf(-v));
}

// ---------------------------------------------------------------------------
// Kernel A: per-channel FULL sums via f4 horizontal sums (memory-bound).
// Unchanged from round 2 (it was not the bottleneck).
// ---------------------------------------------------------------------------
__global__ __launch_bounds__(RED_THREADS) void reduce_kernel(
    const float* __restrict__ x,
    float* __restrict__ S)
{
    const int wave = threadIdx.x >> 6;
    const int lane = threadIdx.x & 63;
    const int gw0 = blockIdx.x * (RED_THREADS / 64) + wave;

    for (int gg = gw0; gg < NGRP_TOTAL; gg += RED_WAVES) {
        const int b  = gg / NGRP;          // magic-mul
        const int gr = gg - b * NGRP;
        const f4* __restrict__ gp = (const f4*)x + (long long)b * NF4 + gr * 225;

        float f0 = 0.f, f1 = 0.f, f2 = 0.f, f3 = 0.f;
#pragma unroll
        for (int j = 0; j < 4; ++j) {
            const int idx = lane + 64 * j;
            if (idx < 225) {
                f4 v = gp[idx];
                const float s1 = v[0] + v[1];
                const float s2 = s1 + v[2];
                const float hs = s2 + v[3];
                const int q = (idx >= 113) ? ((idx >= 169) ? 3 : 2)
                                           : ((idx >= 57) ? 1 : 0);
                // boundary f4s: 56 -> 1|3, 112 -> 2|2, 168 -> 3|1
                const float lo = (idx == 56) ? v[0]
                               : (idx == 112) ? s1
                               : (idx == 168) ? s2 : hs;
                const float hi = hs - lo;   // 0 except at boundaries
                f0 += (q == 0) ? lo : 0.f;
                f1 += (q == 1) ? lo : 0.f;
                f2 += (q == 2) ? lo : 0.f;
                f3 += (q == 3) ? lo : 0.f;
                f1 += (q == 0) ? hi : 0.f;
                f2 += (q == 1) ? hi : 0.f;
                f3 += (q == 2) ? hi : 0.f;
            }
        }
#pragma unroll
        for (int off = 32; off > 0; off >>= 1) {
            f0 += __shfl_down(f0, off, 64);
            f1 += __shfl_down(f1, off, 64);
            f2 += __shfl_down(f2, off, 64);
            f3 += __shfl_down(f3, off, 64);
        }
        if (lane == 0) {
            const float s = 1.0f / 225.0f;
            const int base = b * CC + 4 * gr;
            S[base + 0] = f0 * s;
            S[base + 1] = f1 * s;
            S[base + 2] = f2 * s;
            S[base + 3] = f3 * s;
        }
    }
}

// ---------------------------------------------------------------------------
// Kernel B: gates + streaming scale, fused. One block per (batch, 60-channel
// chunk). Prologue: threads 0-127 compute ring means (center 3x3, 9 scalars
// from L3-resident x) for the block's channel window [C0-2, C0+61] and the
// mirrored window [418-C0, 481-C0]; threads 0-59 then compute the gates
// (full means read from the tiny S array, L2-hot). Main loop: scale with f4
// loads and PLAIN dwordx4 stores (NT removed — suspected write-BW killer).
// ---------------------------------------------------------------------------
__global__ __launch_bounds__(SC_THREADS) void scalegate_kernel(
    const float* __restrict__ x, const float* __restrict__ S,
    const float* __restrict__ w1, const float* __restrict__ b1,
    const float* __restrict__ w2, const float* __restrict__ b2,
    float* __restrict__ out)
{
    __shared__ float RW[64];          // ring means, window [C0-2, C0+61]
    __shared__ float RM[64];          // ring means, mirrored window
    __shared__ float As[CHUNK_CH];    // gates for channels [C0, C0+60)

    const int blk = blockIdx.x;
    const int b = blk >> 3;           // CHUNKS == 8
    const int s = blk & 7;
    const int C0 = s * CHUNK_CH;
    const int t = threadIdx.x;

    // ---- ring means for both windows ----
    if (t < 128) {
        const int ch = (t < 64) ? (C0 - 2 + t) : (418 - C0 + (t - 64));
        float rm = 0.f;
        if ((unsigned)ch < (unsigned)CC) {
            const float* __restrict__ chp = x + (long long)b * CHW + ch * HW;
            rm = (((chp[96] + chp[97] + chp[98])
                 + (chp[111] + chp[112] + chp[113]))
                 + (chp[126] + chp[127] + chp[128])) * (1.0f / 225.0f);
        }
        if (t < 64) RW[t] = rm; else RM[t - 64] = rm;
    }
    __syncthreads();

    // ---- gates for this block's 60 channels ----
    if (t < CHUNK_CH) {
        const int c = C0 + t;
        const float* __restrict__ Ms = S + b * CC;
        float g1 = b1[0], g2 = b2[0];
#pragma unroll
        for (int k = 0; k < 5; ++k) {
            const int j = c + k - 2;
            if (j >= 0 && j < CC) {
                g1 += w1[k] * Ms[j] + w1[5 + k] * Ms[CC - 1 - j];
                g2 += w2[k] * RW[j - (C0 - 2)] + w2[5 + k] * RM[C0 + 61 - j];
            }
        }
        As[t] = sigmoidf((sigmoidf(g1) * sigmoidf(g2) - 0.2f) * 2.0f);
    }
    __syncthreads();

    // ---- streaming scale ----
    const f4* __restrict__ xb = (const f4*)x + (long long)b * NF4 + s * CHUNK_F4;
    f4* __restrict__ ob = (f4*)out + (long long)b * NF4 + s * CHUNK_F4;

#pragma unroll 4
    for (int k = 0; k < SC_FULL_ITERS; ++k) {
        const int g = t + SC_THREADS * k;
        f4 v = xb[g];
        const int e = 4 * g;               // 0..13499, chunk-local
        const int c = e / 225;             // magic-mul; 0..59
        const int rr = e - 225 * c;
        v[0] *= As[c];
        v[1] *= As[c + (rr >= 224)];
        v[2] *= As[c + (rr >= 223)];
        v[3] *= As[c + (rr >= 222)];
        ob[g] = v;                         // plain store (NT removed)
    }
    // tail: 3375 = 13*256 + 47
    if (t < SC_TAIL) {
        const int g = SC_FULL_ITERS * SC_THREADS + t;
        f4 v = xb[g];
        const int e = 4 * g;
        const int c = e / 225;
        const int rr = e - 225 * c;
        v[0] *= As[c];
        v[1] *= As[c + (rr >= 224)];
        v[2] *= As[c + (rr >= 223)];
        v[3] *= As[c + (rr >= 222)];
        ob[g] = v;
    }
}

extern "C" void kernel_launch(void* const* d_in, const int* in_sizes, int n_in,
                              void* d_out, int out_size, void* d_ws, size_t ws_size,
                              hipStream_t stream)
{
    const float* x  = (const float*)d_in[0];
    const float* w1 = (const float*)d_in[1];
    const float* b1 = (const float*)d_in[2];
    const float* w2 = (const float*)d_in[3];
    const float* b2 = (const float*)d_in[4];
    float* out = (float*)d_out;

    float* S = (float*)d_ws;          // [BB][CC] full means (983 KB)

    reduce_kernel<<<RED_BLOCKS, RED_THREADS, 0, stream>>>(x, S);
    scalegate_kernel<<<BB * CHUNKS, SC_THREADS, 0, stream>>>(
        x, S, w1, b1, w2, b2, out);
}

// Round 5
// 429.394 us; speedup vs baseline: 1.0162x; 1.0162x over previous
//
#include <hip/hip_runtime.h>
#include <math.h>

// Problem constants (fixed by setup_inputs)
#define BB 512
#define CC 480              // C1*C2 = 16*30 channels per batch
#define HW 225              // 15*15 pixels per channel
#define CHW (CC * HW)       // 108000 floats per batch
#define NF4 (CHW / 4)       // 27000 float4 per batch
#define NGRP (CC / 4)       // 120 groups of 4 channels (900 floats = 225 f4)
#define NGRP_TOTAL (BB * NGRP)  // 61440 groups over the whole tensor

// Kernel A (reduce): 1920 blocks x 256 thr = 7680 waves, exactly 8 groups/wave.
#define RED_BLOCKS 1920
#define RED_THREADS 256
#define RED_WAVES (RED_BLOCKS * (RED_THREADS / 64))

// Kernel B (gate+scale): 8 chunks per batch, 60 whole channels per chunk.
#define CHUNKS 8
#define CHUNK_F4 (NF4 / CHUNKS)   // 3375 float4 per chunk
#define CHUNK_CH (CC / CHUNKS)    // 60 channels per chunk (13500/225)
#define SC_THREADS 256
#define SC_FULL_ITERS (CHUNK_F4 / SC_THREADS)        // 13
#define SC_TAIL (CHUNK_F4 - SC_FULL_ITERS * SC_THREADS)  // 47

using f4 = __attribute__((ext_vector_type(4))) float;

__device__ __forceinline__ float sigmoidf(float v) {
    return 1.0f / (1.0f + __expf(-v));
}

// ---------------------------------------------------------------------------
// Kernel A: per-channel FULL sums via f4 horizontal sums (memory-bound,
// ~35 us BW floor; VALU share ~6 us/SIMD — not the bottleneck).
// Loads stay NORMAL (allocating): they warm L3 for the scale re-read.
// ---------------------------------------------------------------------------
__global__ __launch_bounds__(RED_THREADS) void reduce_kernel(
    const float* __restrict__ x,
    float* __restrict__ S)
{
    const int wave = threadIdx.x >> 6;
    const int lane = threadIdx.x & 63;
    const int gw0 = blockIdx.x * (RED_THREADS / 64) + wave;

    for (int gg = gw0; gg < NGRP_TOTAL; gg += RED_WAVES) {
        const int b  = gg / NGRP;          // magic-mul
        const int gr = gg - b * NGRP;
        const f4* __restrict__ gp = (const f4*)x + (long long)b * NF4 + gr * 225;

        float f0 = 0.f, f1 = 0.f, f2 = 0.f, f3 = 0.f;
#pragma unroll
        for (int j = 0; j < 4; ++j) {
            const int idx = lane + 64 * j;
            if (idx < 225) {
                f4 v = gp[idx];
                const float s1 = v[0] + v[1];
                const float s2 = s1 + v[2];
                const float hs = s2 + v[3];
                const int q = (idx >= 113) ? ((idx >= 169) ? 3 : 2)
                                           : ((idx >= 57) ? 1 : 0);
                // boundary f4s: 56 -> 1|3, 112 -> 2|2, 168 -> 3|1
                const float lo = (idx == 56) ? v[0]
                               : (idx == 112) ? s1
                               : (idx == 168) ? s2 : hs;
                const float hi = hs - lo;   // 0 except at boundaries
                f0 += (q == 0) ? lo : 0.f;
                f1 += (q == 1) ? lo : 0.f;
                f2 += (q == 2) ? lo : 0.f;
                f3 += (q == 3) ? lo : 0.f;
                f1 += (q == 0) ? hi : 0.f;
                f2 += (q == 1) ? hi : 0.f;
                f3 += (q == 2) ? hi : 0.f;
            }
        }
#pragma unroll
        for (int off = 32; off > 0; off >>= 1) {
            f0 += __shfl_down(f0, off, 64);
            f1 += __shfl_down(f1, off, 64);
            f2 += __shfl_down(f2, off, 64);
            f3 += __shfl_down(f3, off, 64);
        }
        if (lane == 0) {
            const float s = 1.0f / 225.0f;
            const int base = b * CC + 4 * gr;
            S[base + 0] = f0 * s;
            S[base + 1] = f1 * s;
            S[base + 2] = f2 * s;
            S[base + 3] = f3 * s;
        }
    }
}

// ---------------------------------------------------------------------------
// Kernel B: gates + streaming scale, fused. One block per (batch, 60-channel
// chunk). Prologue as round 3. Main loop: NONTEMPORAL loads (x lines are
// consumed for the last time -> don't allocate in L2, leave it for the
// write stream) and NONTEMPORAL stores (proven -20 us vs plain in round 3).
// ---------------------------------------------------------------------------
__global__ __launch_bounds__(SC_THREADS) void scalegate_kernel(
    const float* __restrict__ x, const float* __restrict__ S,
    const float* __restrict__ w1, const float* __restrict__ b1,
    const float* __restrict__ w2, const float* __restrict__ b2,
    float* __restrict__ out)
{
    __shared__ float RW[64];          // ring means, window [C0-2, C0+61]
    __shared__ float RM[64];          // ring means, mirrored window
    __shared__ float As[CHUNK_CH];    // gates for channels [C0, C0+60)

    const int blk = blockIdx.x;
    const int b = blk >> 3;           // CHUNKS == 8
    const int s = blk & 7;
    const int C0 = s * CHUNK_CH;
    const int t = threadIdx.x;

    // ---- ring means for both windows ----
    if (t < 128) {
        const int ch = (t < 64) ? (C0 - 2 + t) : (418 - C0 + (t - 64));
        float rm = 0.f;
        if ((unsigned)ch < (unsigned)CC) {
            const float* __restrict__ chp = x + (long long)b * CHW + ch * HW;
            rm = (((chp[96] + chp[97] + chp[98])
                 + (chp[111] + chp[112] + chp[113]))
                 + (chp[126] + chp[127] + chp[128])) * (1.0f / 225.0f);
        }
        if (t < 64) RW[t] = rm; else RM[t - 64] = rm;
    }
    __syncthreads();

    // ---- gates for this block's 60 channels ----
    if (t < CHUNK_CH) {
        const int c = C0 + t;
        const float* __restrict__ Ms = S + b * CC;
        float g1 = b1[0], g2 = b2[0];
#pragma unroll
        for (int k = 0; k < 5; ++k) {
            const int j = c + k - 2;
            if (j >= 0 && j < CC) {
                g1 += w1[k] * Ms[j] + w1[5 + k] * Ms[CC - 1 - j];
                g2 += w2[k] * RW[j - (C0 - 2)] + w2[5 + k] * RM[C0 + 61 - j];
            }
        }
        As[t] = sigmoidf((sigmoidf(g1) * sigmoidf(g2) - 0.2f) * 2.0f);
    }
    __syncthreads();

    // ---- streaming scale ----
    const f4* __restrict__ xb = (const f4*)x + (long long)b * NF4 + s * CHUNK_F4;
    f4* __restrict__ ob = (f4*)out + (long long)b * NF4 + s * CHUNK_F4;

#pragma unroll 4
    for (int k = 0; k < SC_FULL_ITERS; ++k) {
        const int g = t + SC_THREADS * k;
        f4 v = __builtin_nontemporal_load(&xb[g]);
        const int e = 4 * g;               // 0..13499, chunk-local
        const int c = e / 225;             // magic-mul; 0..59
        const int rr = e - 225 * c;
        v[0] *= As[c];
        v[1] *= As[c + (rr >= 224)];
        v[2] *= As[c + (rr >= 223)];
        v[3] *= As[c + (rr >= 222)];
        __builtin_nontemporal_store(v, &ob[g]);
    }
    // tail: 3375 = 13*256 + 47
    if (t < SC_TAIL) {
        const int g = SC_FULL_ITERS * SC_THREADS + t;
        f4 v = __builtin_nontemporal_load(&xb[g]);
        const int e = 4 * g;
        const int c = e / 225;
        const int rr = e - 225 * c;
        v[0] *= As[c];
        v[1] *= As[c + (rr >= 224)];
        v[2] *= As[c + (rr >= 223)];
        v[3] *= As[c + (rr >= 222)];
        __builtin_nontemporal_store(v, &ob[g]);
    }
}

extern "C" void kernel_launch(void* const* d_in, const int* in_sizes, int n_in,
                              void* d_out, int out_size, void* d_ws, size_t ws_size,
                              hipStream_t stream)
{
    const float* x  = (const float*)d_in[0];
    const float* w1 = (const float*)d_in[1];
    const float* b1 = (const float*)d_in[2];
    const float* w2 = (const float*)d_in[3];
    const float* b2 = (const float*)d_in[4];
    float* out = (float*)d_out;

    float* S = (float*)d_ws;          // [BB][CC] full means (983 KB)

    reduce_kernel<<<RED_BLOCKS, RED_THREADS, 0, stream>>>(x, S);
    scalegate_kernel<<<BB * CHUNKS, SC_THREADS, 0, stream>>>(
        x, S, w1, b1, w2, b2, out);
}

// Round 6
// 411.490 us; speedup vs baseline: 1.0604x; 1.0435x over previous
//
#include <hip/hip_runtime.h>
#include <math.h>

// Problem constants (fixed by setup_inputs)
#define BB 512
#define CC 480              // C1*C2 = 16*30 channels per batch
#define HW 225              // 15*15 pixels per channel
#define CHW (CC * HW)       // 108000 floats per batch
#define NF4 (CHW / 4)       // 27000 float4 per batch
#define NGRP_B 120          // 4-channel groups per batch (900 floats = 225 f4)
#define NTHREADS 1024
#define NWAVES (NTHREADS / 64)   // 16

using f4 = __attribute__((ext_vector_type(4))) float;

__device__ __forceinline__ float sigmoidf(float v) {
    return 1.0f / (1.0f + __expf(-v));
}

// ---------------------------------------------------------------------------
// One block per batch (512 blocks x 1024 thr = 2 blocks/CU, 32 waves/CU).
// Rationale: the batch's 432 KB is re-read ~50 us after the reduce read it,
// so the re-read hits L2/L3 (the split-kernel version cycled the whole
// 221 MB of x through L3 between read and re-read -> HBM re-fetch).
//
// Phase 1: cheap hsum per-channel full sums (R2-proven, BW-bound) -> LDS.
// Phase 2: ring means via 9 scalar L2/L3-hot loads per channel + gates (R2).
// Phase 3: streaming scale, NT load (last use) + NT store (R3: plain costs
//          +20 us; NT keeps the write stream from thrashing the caches).
// Only block-local barriers; no workspace; one launch.
// ---------------------------------------------------------------------------
__global__ __launch_bounds__(NTHREADS) void fused_kernel(
    const float* __restrict__ x,
    const float* __restrict__ w1, const float* __restrict__ b1,
    const float* __restrict__ w2, const float* __restrict__ b2,
    float* __restrict__ out)
{
    __shared__ float Ms[CC];   // full means
    __shared__ float Rs[CC];   // ring (center 3x3) means
    __shared__ float As[CC];   // gates

    const int b = blockIdx.x;
    const int t = threadIdx.x;
    const int wave = t >> 6;
    const int lane = t & 63;

    const f4* __restrict__ xb4 = (const f4*)(x + (long long)b * CHW);

    // ---------------- Phase 1: per-channel full sums (hsum trick) ----------
    // A 4-channel group = 900 floats = 225 f4; channel boundaries split only
    // f4 #56 (1|3), #112 (2|2), #168 (3|1).
    for (int gr = wave; gr < NGRP_B; gr += NWAVES) {
        const f4* __restrict__ gp = xb4 + gr * 225;
        float f0 = 0.f, f1 = 0.f, f2 = 0.f, f3 = 0.f;
#pragma unroll
        for (int j = 0; j < 4; ++j) {
            const int idx = lane + 64 * j;
            if (idx < 225) {
                f4 v = gp[idx];
                const float s1 = v[0] + v[1];
                const float s2 = s1 + v[2];
                const float hs = s2 + v[3];
                const int q = (idx >= 113) ? ((idx >= 169) ? 3 : 2)
                                           : ((idx >= 57) ? 1 : 0);
                const float lo = (idx == 56) ? v[0]
                               : (idx == 112) ? s1
                               : (idx == 168) ? s2 : hs;
                const float hi = hs - lo;   // 0 except at boundaries
                f0 += (q == 0) ? lo : 0.f;
                f1 += (q == 1) ? lo : 0.f;
                f2 += (q == 2) ? lo : 0.f;
                f3 += (q == 3) ? lo : 0.f;
                f1 += (q == 0) ? hi : 0.f;
                f2 += (q == 1) ? hi : 0.f;
                f3 += (q == 2) ? hi : 0.f;
            }
        }
#pragma unroll
        for (int off = 32; off > 0; off >>= 1) {
            f0 += __shfl_down(f0, off, 64);
            f1 += __shfl_down(f1, off, 64);
            f2 += __shfl_down(f2, off, 64);
            f3 += __shfl_down(f3, off, 64);
        }
        if (lane == 0) {
            const float s = 1.0f / 225.0f;
            Ms[4 * gr + 0] = f0 * s;
            Ms[4 * gr + 1] = f1 * s;
            Ms[4 * gr + 2] = f2 * s;
            Ms[4 * gr + 3] = f3 * s;
        }
    }
    __syncthreads();

    // ---------------- Phase 2a: ring means (center 3x3, 9 scalars) ---------
    if (t < CC) {
        const float* __restrict__ ch = x + (long long)b * CHW + t * HW;
        const float r = ((ch[96] + ch[97] + ch[98])
                       + (ch[111] + ch[112] + ch[113]))
                       + (ch[126] + ch[127] + ch[128]);
        Rs[t] = r * (1.0f / 225.0f);
    }
    __syncthreads();

    // ---------------- Phase 2b: gates --------------------------------------
    if (t < CC) {
        const int c = t;
        float g1 = b1[0], g2 = b2[0];
#pragma unroll
        for (int k = 0; k < 5; ++k) {
            const int j = c + k - 2;
            if (j >= 0 && j < CC) {
                g1 += w1[k] * Ms[j] + w1[5 + k] * Ms[CC - 1 - j];
                g2 += w2[k] * Rs[j] + w2[5 + k] * Rs[CC - 1 - j];
            }
        }
        As[c] = sigmoidf((sigmoidf(g1) * sigmoidf(g2) - 0.2f) * 2.0f);
    }
    __syncthreads();

    // ---------------- Phase 3: streaming scale -----------------------------
    f4* __restrict__ ob4 = (f4*)(out + (long long)b * CHW);
    for (int g = t; g < NF4; g += NTHREADS) {
        f4 v = __builtin_nontemporal_load(&xb4[g]);
        const int e = 4 * g;
        const int c0 = e / 225;            // magic-mul, 0..479
        const int rr = e - 225 * c0;
        v[0] *= As[c0];
        v[1] *= As[c0 + (rr >= 224)];
        v[2] *= As[c0 + (rr >= 223)];
        v[3] *= As[c0 + (rr >= 222)];
        __builtin_nontemporal_store(v, &ob4[g]);
    }
}

extern "C" void kernel_launch(void* const* d_in, const int* in_sizes, int n_in,
                              void* d_out, int out_size, void* d_ws, size_t ws_size,
                              hipStream_t stream)
{
    const float* x  = (const float*)d_in[0];
    const float* w1 = (const float*)d_in[1];
    const float* b1 = (const float*)d_in[2];
    const float* w2 = (const float*)d_in[3];
    const float* b2 = (const float*)d_in[4];
    float* out = (float*)d_out;

    fused_kernel<<<BB, NTHREADS, 0, stream>>>(x, w1, b1, w2, b2, out);
}